// Round 1
// baseline (5013.131 us; speedup 1.0000x reference)
//
#include <hip/hip_runtime.h>

#define Dm 1024
#define Sm 2048
#define Bm 2
#define Lm 6
#define Fm 4096
#define Vm 32000
#define MT (Bm*Sm)   // 4096 tokens

typedef unsigned short u16;
typedef unsigned int   u32;
typedef __attribute__((ext_vector_type(8))) short bf16x8;
typedef __attribute__((ext_vector_type(4))) float f32x4;

__device__ __forceinline__ u16 f2bf(float f) {
  u32 u = __float_as_uint(f);
  u += 0x7fffu + ((u >> 16) & 1u);
  return (u16)(u >> 16);
}
__device__ __forceinline__ u32 pack2(float a, float b) {
  return (u32)f2bf(a) | ((u32)f2bf(b) << 16);
}

// ---------------- embed: h = embed_table[tok] + pos ----------------
__global__ __launch_bounds__(256) void embed_kernel(
    const int* __restrict__ tok, const float* __restrict__ emb,
    const float* __restrict__ pos, float* __restrict__ h)
{
  int i  = blockIdx.x * 256 + threadIdx.x;   // element-quads
  int d  = (i & (Dm/4 - 1)) * 4;
  int bs = i >> 8;                            // Dm/4 == 256
  int s  = bs & (Sm - 1);
  int t  = tok[bs];
  float4 e = *(const float4*)(emb + (size_t)t * Dm + d);
  float4 p = *(const float4*)(pos + (size_t)s * Dm + d);
  float4 r; r.x = e.x + p.x; r.y = e.y + p.y; r.z = e.z + p.z; r.w = e.w + p.w;
  *(float4*)(h + (size_t)bs * Dm + d) = r;
}

// ---------------- LayerNorm (fp32 in, bf16 out) ----------------
__global__ __launch_bounds__(256) void ln_kernel(
    const float* __restrict__ x, const float* __restrict__ w,
    const float* __restrict__ b, u16* __restrict__ o)
{
  __shared__ float red[8];
  int row = blockIdx.x, tid = threadIdx.x;
  const float* xr = x + (size_t)row * Dm;
  float4 v = *(const float4*)(xr + tid * 4);
  float s1 = v.x + v.y + v.z + v.w;
  float s2 = v.x*v.x + v.y*v.y + v.z*v.z + v.w*v.w;
  #pragma unroll
  for (int off = 32; off; off >>= 1) {
    s1 += __shfl_down(s1, off, 64);
    s2 += __shfl_down(s2, off, 64);
  }
  int lane = tid & 63, wv = tid >> 6;
  if (!lane) { red[wv] = s1; red[4 + wv] = s2; }
  __syncthreads();
  s1 = red[0] + red[1] + red[2] + red[3];
  s2 = red[4] + red[5] + red[6] + red[7];
  float mu = s1 * (1.f / Dm);
  float rs = rsqrtf(s2 * (1.f / Dm) - mu * mu + 1e-5f);
  float4 wv4 = *(const float4*)(w + tid * 4);
  float4 bv4 = *(const float4*)(b + tid * 4);
  uint2 pk;
  pk.x = pack2((v.x - mu) * rs * wv4.x + bv4.x, (v.y - mu) * rs * wv4.y + bv4.y);
  pk.y = pack2((v.z - mu) * rs * wv4.z + bv4.z, (v.w - mu) * rs * wv4.w + bv4.w);
  *(uint2*)(o + (size_t)row * Dm + tid * 4) = pk;
}

// ---------------- causal softmax over scores/32 (fp32 in, bf16 out) ----------------
__global__ __launch_bounds__(256) void softmax_kernel(
    const float* __restrict__ sc, u16* __restrict__ at)
{
  __shared__ float red[8];
  int gr = blockIdx.x;
  int s  = gr & (Sm - 1);
  const float* x = sc + (size_t)gr * Sm;
  u16* o = at + (size_t)gr * Sm;
  int tid = threadIdx.x;
  float4 v0 = *(const float4*)(x + tid * 8);
  float4 v1 = *(const float4*)(x + tid * 8 + 4);
  float vals[8] = {v0.x, v0.y, v0.z, v0.w, v1.x, v1.y, v1.z, v1.w};
  float mx = -1e30f;
  #pragma unroll
  for (int j = 0; j < 8; ++j) {
    int t = tid * 8 + j;
    vals[j] = (t <= s) ? vals[j] * 0.03125f : -1e30f;  // /sqrt(1024)
    mx = fmaxf(mx, vals[j]);
  }
  #pragma unroll
  for (int off = 32; off; off >>= 1) mx = fmaxf(mx, __shfl_down(mx, off, 64));
  int lane = tid & 63, wv = tid >> 6;
  if (!lane) red[wv] = mx;
  __syncthreads();
  mx = fmaxf(fmaxf(red[0], red[1]), fmaxf(red[2], red[3]));
  __syncthreads();
  float e[8], sm = 0.f;
  #pragma unroll
  for (int j = 0; j < 8; ++j) {
    int t = tid * 8 + j;
    e[j] = (t <= s) ? __expf(vals[j] - mx) : 0.f;
    sm += e[j];
  }
  #pragma unroll
  for (int off = 32; off; off >>= 1) sm += __shfl_down(sm, off, 64);
  if (!lane) red[wv] = sm;
  __syncthreads();
  sm = red[0] + red[1] + red[2] + red[3];
  float inv = 1.f / sm;
  uint4 p;
  p.x = pack2(e[0]*inv, e[1]*inv); p.y = pack2(e[2]*inv, e[3]*inv);
  p.z = pack2(e[4]*inv, e[5]*inv); p.w = pack2(e[6]*inv, e[7]*inv);
  *(uint4*)(o + tid * 8) = p;
}

// ---------------- fp32 -> bf16 copy ----------------
__global__ __launch_bounds__(256) void tobf16_kernel(
    const float* __restrict__ x, u16* __restrict__ o)
{
  int i = (blockIdx.x * 256 + threadIdx.x) * 4;
  float4 v = *(const float4*)(x + i);
  uint2 pk; pk.x = pack2(v.x, v.y); pk.y = pack2(v.z, v.w);
  *(uint2*)(o + i) = pk;
}

// ---------------- GEMM: C[M,N] = A[M,K] * B[N,K]^T (+epilogue) ----------------
// 128x128 tile, BK=64, 4 waves (2x2), mfma_f32_16x16x32_bf16.
// A/B staged to LDS with fp32->bf16 conversion when *F32; XOR swizzle
// byte ^= (row&7)<<4 kills the 128B-stride bank conflict (guide G4).
enum { EPI_F32 = 0, EPI_RELU_BF16 = 1, EPI_QKV = 2, EPI_RES = 3 };

template<bool AF32, bool BF32>
__global__ __launch_bounds__(256, 2)
void gemm_kernel(const void* __restrict__ Ap, const void* __restrict__ Bp,
                 float* __restrict__ outF, u16* __restrict__ outB,
                 const float* __restrict__ bias, const float* __restrict__ resid,
                 u16* __restrict__ qp, u16* __restrict__ kp, u16* __restrict__ vp,
                 int M, int N, int K,
                 long sA, long sB, long sO, long sR, int epi)
{
  __shared__ __align__(16) short As[128 * 64];
  __shared__ __align__(16) short Bs[128 * 64];

  const int z  = blockIdx.z;
  const int m0 = blockIdx.y * 128;
  const int n0 = blockIdx.x * 128;
  const int tid = threadIdx.x;

  const void* Az = AF32 ? (const void*)((const float*)Ap + (size_t)z * sA)
                        : (const void*)((const u16*)Ap + (size_t)z * sA);
  const void* Bz = BF32 ? (const void*)((const float*)Bp + (size_t)z * sB)
                        : (const void*)((const u16*)Bp + (size_t)z * sB);

  const int srow = tid >> 1;           // 0..127
  const int scol = (tid & 1) * 32;     // 0 or 32 (elements)
  const int swz  = (srow & 7) << 4;

  const int lane = tid & 63;
  const int wid  = tid >> 6;
  const int wm   = (wid >> 1) * 64;
  const int wn   = (wid & 1) * 64;
  const int lrow = lane & 15;
  const int kgrp = lane >> 4;

  f32x4 acc[4][4];
  #pragma unroll
  for (int i = 0; i < 4; ++i)
    #pragma unroll
    for (int j = 0; j < 4; ++j)
      acc[i][j] = (f32x4){0.f, 0.f, 0.f, 0.f};

  for (int k0 = 0; k0 < K; k0 += 64) {
    __syncthreads();
    {  // stage A tile [128][64]
      char* dst = (char*)As + srow * 128;
      if constexpr (AF32) {
        const float* g = (const float*)Az + (size_t)(m0 + srow) * K + k0 + scol;
        #pragma unroll
        for (int j = 0; j < 4; ++j) {
          float4 f0 = *(const float4*)(g + j * 8);
          float4 f1 = *(const float4*)(g + j * 8 + 4);
          uint4 pkv;
          pkv.x = pack2(f0.x, f0.y); pkv.y = pack2(f0.z, f0.w);
          pkv.z = pack2(f1.x, f1.y); pkv.w = pack2(f1.z, f1.w);
          *(uint4*)(dst + (((scol + j * 8) * 2) ^ swz)) = pkv;
        }
      } else {
        const u16* g = (const u16*)Az + (size_t)(m0 + srow) * K + k0 + scol;
        #pragma unroll
        for (int j = 0; j < 4; ++j)
          *(uint4*)(dst + (((scol + j * 8) * 2) ^ swz)) = *(const uint4*)(g + j * 8);
      }
    }
    {  // stage B tile [128][64]
      char* dst = (char*)Bs + srow * 128;
      if constexpr (BF32) {
        const float* g = (const float*)Bz + (size_t)(n0 + srow) * K + k0 + scol;
        #pragma unroll
        for (int j = 0; j < 4; ++j) {
          float4 f0 = *(const float4*)(g + j * 8);
          float4 f1 = *(const float4*)(g + j * 8 + 4);
          uint4 pkv;
          pkv.x = pack2(f0.x, f0.y); pkv.y = pack2(f0.z, f0.w);
          pkv.z = pack2(f1.x, f1.y); pkv.w = pack2(f1.z, f1.w);
          *(uint4*)(dst + (((scol + j * 8) * 2) ^ swz)) = pkv;
        }
      } else {
        const u16* g = (const u16*)Bz + (size_t)(n0 + srow) * K + k0 + scol;
        #pragma unroll
        for (int j = 0; j < 4; ++j)
          *(uint4*)(dst + (((scol + j * 8) * 2) ^ swz)) = *(const uint4*)(g + j * 8);
      }
    }
    __syncthreads();
    #pragma unroll
    for (int kk = 0; kk < 2; ++kk) {
      bf16x8 af[4], bf_[4];
      #pragma unroll
      for (int i = 0; i < 4; ++i) {
        int ar = wm + i * 16 + lrow;
        af[i]  = *(const bf16x8*)((const char*)As + ar * 128 +
                                  ((kk * 64 + kgrp * 16) ^ ((ar & 7) << 4)));
        int br = wn + i * 16 + lrow;
        bf_[i] = *(const bf16x8*)((const char*)Bs + br * 128 +
                                  ((kk * 64 + kgrp * 16) ^ ((br & 7) << 4)));
      }
      #pragma unroll
      for (int i = 0; i < 4; ++i)
        #pragma unroll
        for (int j = 0; j < 4; ++j)
          acc[i][j] = __builtin_amdgcn_mfma_f32_16x16x32_bf16(af[i], bf_[j], acc[i][j], 0, 0, 0);
    }
  }

  // epilogue: C layout col=lane&15, row=(lane>>4)*4+r  [guide m89]
  #pragma unroll
  for (int i = 0; i < 4; ++i) {
    #pragma unroll
    for (int j = 0; j < 4; ++j) {
      #pragma unroll
      for (int r = 0; r < 4; ++r) {
        int m = m0 + wm + i * 16 + kgrp * 4 + r;
        int n = n0 + wn + j * 16 + lrow;
        float v = acc[i][j][r];
        if (bias) v += bias[n];
        if (epi == EPI_F32) {
          outF[(size_t)z * sO + (size_t)m * N + n] = v;
        } else if (epi == EPI_RELU_BF16) {
          outB[(size_t)m * N + n] = f2bf(fmaxf(v, 0.f));
        } else if (epi == EPI_RES) {
          float* o = outF + (size_t)z * sO;
          const float* rsd = resid + (size_t)z * sR;
          o[(size_t)m * N + n] = rsd[(size_t)m * N + n] + v;
        } else {  // EPI_QKV: split q | k | v^T
          u16 hv = f2bf(v);
          if (n < 1024)      qp[(size_t)m * Dm + n] = hv;
          else if (n < 2048) kp[(size_t)m * Dm + (n - 1024)] = hv;
          else vp[(((size_t)(m >> 11)) << 21) + (size_t)(n - 2048) * Sm + (m & (Sm - 1))] = hv;
        }
      }
    }
  }
}

extern "C" void kernel_launch(void* const* d_in, const int* in_sizes, int n_in,
                              void* d_out, int out_size, void* d_ws, size_t ws_size,
                              hipStream_t stream)
{
  const int*   tok  = (const int*)d_in[0];
  const float* emb  = (const float*)d_in[1];
  const float* pos  = (const float*)d_in[2];
  const float* ln1w = (const float*)d_in[3];
  const float* ln1b = (const float*)d_in[4];
  const float* qkvw = (const float*)d_in[5];
  const float* qkvb = (const float*)d_in[6];
  const float* ln2w = (const float*)d_in[7];
  const float* ln2b = (const float*)d_in[8];
  const float* ffaw = (const float*)d_in[9];
  const float* ffab = (const float*)d_in[10];
  const float* ffbw = (const float*)d_in[11];
  const float* ffbb = (const float*)d_in[12];
  const float* outw = (const float*)d_in[13];
  float* out = (float*)d_out;

  // workspace layout (~136 MiB)
  char* p = (char*)d_ws;
  float* h      = (float*)p;  p += (size_t)MT * Dm * 4;
  u16*   a      = (u16*)p;    p += (size_t)MT * Dm * 2;
  u16*   hb     = (u16*)p;    p += (size_t)MT * Dm * 2;
  u16*   q      = (u16*)p;    p += (size_t)Bm * Sm * Dm * 2;
  u16*   kbuf   = (u16*)p;    p += (size_t)Bm * Sm * Dm * 2;
  u16*   vT     = (u16*)p;    p += (size_t)Bm * Dm * Sm * 2;
  float* scores = (float*)p;  p += (size_t)Bm * Sm * Sm * 4;
  u16*   attn   = (u16*)p;    p += (size_t)Bm * Sm * Sm * 2;
  u16*   f      = (u16*)p;    p += (size_t)MT * Fm * 2;

  embed_kernel<<<MT * Dm / 1024, 256, 0, stream>>>(tok, emb, pos, h);

  for (int l = 0; l < Lm; ++l) {
    ln_kernel<<<MT, 256, 0, stream>>>(h, ln1w + l * Dm, ln1b + l * Dm, a);
    // qkv = a * qkv_w^T + b   -> q,k bf16 [B,S,D]; v stored transposed [B,D,S]
    gemm_kernel<false, true><<<dim3(3 * Dm / 128, MT / 128, 1), 256, 0, stream>>>(
        a, qkvw + (size_t)l * 3 * Dm * Dm, nullptr, nullptr, qkvb + l * 3 * Dm, nullptr,
        q, kbuf, vT, MT, 3 * Dm, Dm, 0, 0, 0, 0, EPI_QKV);
    // scores[b] = q_b * k_b^T  (fp32)
    gemm_kernel<false, false><<<dim3(Sm / 128, Sm / 128, Bm), 256, 0, stream>>>(
        q, kbuf, scores, nullptr, nullptr, nullptr, nullptr, nullptr, nullptr,
        Sm, Sm, Dm, (long)Sm * Dm, (long)Sm * Dm, (long)Sm * Sm, 0, EPI_F32);
    softmax_kernel<<<Bm * Sm, 256, 0, stream>>>(scores, attn);
    // h += attn * v  ( = attn * vT^T )
    gemm_kernel<false, false><<<dim3(Dm / 128, Sm / 128, Bm), 256, 0, stream>>>(
        attn, vT, h, nullptr, nullptr, h, nullptr, nullptr, nullptr,
        Sm, Dm, Sm, (long)Sm * Sm, (long)Dm * Sm, (long)Sm * Dm, (long)Sm * Dm, EPI_RES);
    ln_kernel<<<MT, 256, 0, stream>>>(h, ln2w + l * Dm, ln2b + l * Dm, a);
    // f = relu(a * ffa_w^T + b)  (bf16)
    gemm_kernel<false, true><<<dim3(Fm / 128, MT / 128, 1), 256, 0, stream>>>(
        a, ffaw + (size_t)l * Fm * Dm, nullptr, f, ffab + l * Fm, nullptr,
        nullptr, nullptr, nullptr, MT, Fm, Dm, 0, 0, 0, 0, EPI_RELU_BF16);
    // h += f * ffb_w^T + b
    gemm_kernel<false, true><<<dim3(Dm / 128, MT / 128, 1), 256, 0, stream>>>(
        f, ffbw + (size_t)l * Dm * Fm, h, nullptr, ffbb + l * Dm, h,
        nullptr, nullptr, nullptr, MT, Dm, Fm, 0, 0, 0, 0, EPI_RES);
  }

  tobf16_kernel<<<MT * Dm / 1024, 256, 0, stream>>>(h, hb);
  // logits = h * out_w^T  (fp32 out)
  gemm_kernel<false, true><<<dim3(Vm / 128, MT / 128, 1), 256, 0, stream>>>(
      hb, outw, out, nullptr, nullptr, nullptr, nullptr, nullptr, nullptr,
      MT, Vm, Dm, 0, 0, 0, 0, EPI_F32);
}

// Round 2
// 2244.900 us; speedup vs baseline: 2.2331x; 2.2331x over previous
//
#include <hip/hip_runtime.h>

#define Dm 1024
#define Sm 2048
#define Bm 2
#define Lm 6
#define Fm 4096
#define Vm 32000
#define MT (Bm*Sm)   // 4096 tokens

typedef unsigned short u16;
typedef unsigned int   u32;
typedef __attribute__((ext_vector_type(8))) short bf16x8;
typedef __attribute__((ext_vector_type(4))) float f32x4;

__device__ __forceinline__ u16 f2bf(float f) {
  u32 u = __float_as_uint(f);
  u += 0x7fffu + ((u >> 16) & 1u);
  return (u16)(u >> 16);
}
__device__ __forceinline__ u32 pack2(float a, float b) {
  return (u32)f2bf(a) | ((u32)f2bf(b) << 16);
}
__device__ __forceinline__ void gload16(const void* g, void* l) {
  __builtin_amdgcn_global_load_lds(
      (const __attribute__((address_space(1))) void*)g,
      (__attribute__((address_space(3))) void*)l, 16, 0, 0);
}

// ---------------- embed: h = embed_table[tok] + pos ----------------
__global__ __launch_bounds__(256) void embed_kernel(
    const int* __restrict__ tok, const float* __restrict__ emb,
    const float* __restrict__ pos, float* __restrict__ h)
{
  int i  = blockIdx.x * 256 + threadIdx.x;   // element-quads
  int d  = (i & (Dm/4 - 1)) * 4;
  int bs = i >> 8;                            // Dm/4 == 256
  int s  = bs & (Sm - 1);
  int t  = tok[bs];
  float4 e = *(const float4*)(emb + (size_t)t * Dm + d);
  float4 p = *(const float4*)(pos + (size_t)s * Dm + d);
  float4 r; r.x = e.x + p.x; r.y = e.y + p.y; r.z = e.z + p.z; r.w = e.w + p.w;
  *(float4*)(h + (size_t)bs * Dm + d) = r;
}

// ---------------- LayerNorm (fp32 in, bf16 out) ----------------
__global__ __launch_bounds__(256) void ln_kernel(
    const float* __restrict__ x, const float* __restrict__ w,
    const float* __restrict__ b, u16* __restrict__ o)
{
  __shared__ float red[8];
  int row = blockIdx.x, tid = threadIdx.x;
  const float* xr = x + (size_t)row * Dm;
  float4 v = *(const float4*)(xr + tid * 4);
  float s1 = v.x + v.y + v.z + v.w;
  float s2 = v.x*v.x + v.y*v.y + v.z*v.z + v.w*v.w;
  #pragma unroll
  for (int off = 32; off; off >>= 1) {
    s1 += __shfl_down(s1, off, 64);
    s2 += __shfl_down(s2, off, 64);
  }
  int lane = tid & 63, wv = tid >> 6;
  if (!lane) { red[wv] = s1; red[4 + wv] = s2; }
  __syncthreads();
  s1 = red[0] + red[1] + red[2] + red[3];
  s2 = red[4] + red[5] + red[6] + red[7];
  float mu = s1 * (1.f / Dm);
  float rs = rsqrtf(s2 * (1.f / Dm) - mu * mu + 1e-5f);
  float4 wv4 = *(const float4*)(w + tid * 4);
  float4 bv4 = *(const float4*)(b + tid * 4);
  uint2 pk;
  pk.x = pack2((v.x - mu) * rs * wv4.x + bv4.x, (v.y - mu) * rs * wv4.y + bv4.y);
  pk.y = pack2((v.z - mu) * rs * wv4.z + bv4.z, (v.w - mu) * rs * wv4.w + bv4.w);
  *(uint2*)(o + (size_t)row * Dm + tid * 4) = pk;
}

// ---------------- causal softmax over scores/32 (fp32 in, bf16 out) ----------------
__global__ __launch_bounds__(256) void softmax_kernel(
    const float* __restrict__ sc, u16* __restrict__ at)
{
  __shared__ float red[8];
  int gr = blockIdx.x;
  int s  = gr & (Sm - 1);
  const float* x = sc + (size_t)gr * Sm;
  u16* o = at + (size_t)gr * Sm;
  int tid = threadIdx.x;
  float4 v0 = *(const float4*)(x + tid * 8);
  float4 v1 = *(const float4*)(x + tid * 8 + 4);
  float vals[8] = {v0.x, v0.y, v0.z, v0.w, v1.x, v1.y, v1.z, v1.w};
  float mx = -1e30f;
  #pragma unroll
  for (int j = 0; j < 8; ++j) {
    int t = tid * 8 + j;
    vals[j] = (t <= s) ? vals[j] * 0.03125f : -1e30f;  // /sqrt(1024)
    mx = fmaxf(mx, vals[j]);
  }
  #pragma unroll
  for (int off = 32; off; off >>= 1) mx = fmaxf(mx, __shfl_down(mx, off, 64));
  int lane = tid & 63, wv = tid >> 6;
  if (!lane) red[wv] = mx;
  __syncthreads();
  mx = fmaxf(fmaxf(red[0], red[1]), fmaxf(red[2], red[3]));
  __syncthreads();
  float e[8], sm = 0.f;
  #pragma unroll
  for (int j = 0; j < 8; ++j) {
    int t = tid * 8 + j;
    e[j] = (t <= s) ? __expf(vals[j] - mx) : 0.f;
    sm += e[j];
  }
  #pragma unroll
  for (int off = 32; off; off >>= 1) sm += __shfl_down(sm, off, 64);
  if (!lane) red[wv] = sm;
  __syncthreads();
  sm = red[0] + red[1] + red[2] + red[3];
  float inv = 1.f / sm;
  uint4 p;
  p.x = pack2(e[0]*inv, e[1]*inv); p.y = pack2(e[2]*inv, e[3]*inv);
  p.z = pack2(e[4]*inv, e[5]*inv); p.w = pack2(e[6]*inv, e[7]*inv);
  *(uint4*)(o + tid * 8) = p;
}

// ---------------- fp32 -> bf16, 8 elems/thread ----------------
__global__ __launch_bounds__(256) void cvt8_kernel(
    const float* __restrict__ x, u16* __restrict__ o)
{
  size_t i = ((size_t)blockIdx.x * 256 + threadIdx.x) * 8;
  float4 v0 = *(const float4*)(x + i);
  float4 v1 = *(const float4*)(x + i + 4);
  uint4 p; p.x = pack2(v0.x, v0.y); p.y = pack2(v0.z, v0.w);
  p.z = pack2(v1.x, v1.y); p.w = pack2(v1.z, v1.w);
  *(uint4*)(o + i) = p;
}

// ---------------- per-layer weight convert: qkv|ffa|ffb -> wlb (bf16) ----------------
__global__ __launch_bounds__(256) void cvtw_kernel(
    const float* __restrict__ qw, const float* __restrict__ aw,
    const float* __restrict__ bw, u16* __restrict__ o)
{
  int b = blockIdx.x;
  const float* src; u16* dst; int idx;
  if (b < 1536)      { src = qw; dst = o;                     idx = b; }
  else if (b < 3584) { src = aw; dst = o + 3*Dm*Dm;           idx = b - 1536; }
  else               { src = bw; dst = o + 3*Dm*Dm + Fm*Dm;   idx = b - 3584; }
  size_t i = ((size_t)idx * 256 + threadIdx.x) * 8;
  float4 v0 = *(const float4*)(src + i);
  float4 v1 = *(const float4*)(src + i + 4);
  uint4 p; p.x = pack2(v0.x, v0.y); p.y = pack2(v0.z, v0.w);
  p.z = pack2(v1.x, v1.y); p.w = pack2(v1.z, v1.w);
  *(uint4*)(dst + i) = p;
}

// ---------------- V transpose: qkv[:, 2048:3072] -> vT [B][D][S] ----------------
__global__ __launch_bounds__(256) void vtr_kernel(
    const u16* __restrict__ v, u16* __restrict__ vT)
{
  __shared__ u16 t[64][64];
  int b = blockIdx.z;
  int s0 = blockIdx.x * 64, d0 = blockIdx.y * 64;
  const u16* src = v + ((size_t)b * Sm + s0) * (3 * Dm) + d0;
  int tid = threadIdx.x;
  int rr = tid >> 3, cc = (tid & 7) * 8;
  #pragma unroll
  for (int it = 0; it < 2; ++it) {
    int r = rr + it * 32;
    uint4 x = *(const uint4*)(src + (size_t)r * (3 * Dm) + cc);
    *(uint4*)&t[r][cc ^ (((r >> 3) & 7) << 3)] = x;
  }
  __syncthreads();
  u16* dst = vT + ((size_t)b * Dm + d0) * Sm + s0;
  #pragma unroll
  for (int it = 0; it < 2; ++it) {
    int d = rr + it * 32;
    u16 tmp[8];
    #pragma unroll
    for (int j = 0; j < 8; ++j) {
      int r = cc + j;
      tmp[j] = t[r][d ^ (((r >> 3) & 7) << 3)];
    }
    *(uint4*)(dst + (size_t)d * Sm + cc) = *(uint4*)tmp;
  }
}

// ---------------- GEMM: C[M,N] = A[M,K] * B[N,K]^T (+epilogue), all bf16 in ----------------
// 128x128 tile, BK=64, 4 waves (2x2), mfma_f32_16x16x32_bf16.
// global_load_lds width-16 staging, LDS linear, XOR swizzle byte^=(row&7)<<4
// applied by PRE-SWIZZLING the global source address (guide m173).
// M-fastest tile order + bijective XCD chunk swizzle when swz!=0.
enum { EPI_F32 = 0, EPI_BF16 = 1, EPI_RELU_BF16 = 2, EPI_RES = 3 };

__global__ __launch_bounds__(256, 2)
void gemm_kernel(const u16* __restrict__ A, const u16* __restrict__ B,
                 float* __restrict__ outF, u16* __restrict__ outB,
                 const float* __restrict__ bias, const float* __restrict__ resid,
                 int N, int K, int lda, int ldb,
                 long sA, long sB, long sO, long sR,
                 int mshift, int epi, int swz)
{
  __shared__ __align__(16) short As[128 * 64];
  __shared__ __align__(16) short Bs[128 * 64];

  const int z = blockIdx.z;
  int bid = blockIdx.x;
  if (swz) { int cpx = gridDim.x >> 3; bid = (bid & 7) * cpx + (bid >> 3); }
  const int m0 = (bid & ((1 << mshift) - 1)) << 7;
  const int n0 = (bid >> mshift) << 7;

  const u16* Az = A + (size_t)z * sA;
  const u16* Bz = B + (size_t)z * sB;

  const int tid = threadIdx.x;
  const int l   = tid & 63;
  const int w   = tid >> 6;
  const int sub = l >> 3;                       // row-within-8
  const int colb = ((l & 7) ^ sub) << 4;        // pre-swizzled source byte-col
  const int row0 = w * 32 + sub;                // + c*8 per chunk

  const char* gA = (const char*)(Az + (size_t)(m0 + row0) * lda) + colb;
  const char* gB = (const char*)(Bz + (size_t)(n0 + row0) * ldb) + colb;
  const size_t stepA = (size_t)8 * lda * 2;     // 8 rows, bytes
  const size_t stepB = (size_t)8 * ldb * 2;
  char* lA = (char*)As + w * 4096;
  char* lB = (char*)Bs + w * 4096;

  const int wm   = (w >> 1) * 64;
  const int wn   = (w & 1) * 64;
  const int lrow = l & 15;
  const int kgrp = l >> 4;

  f32x4 acc[4][4];
  #pragma unroll
  for (int i = 0; i < 4; ++i)
    #pragma unroll
    for (int j = 0; j < 4; ++j)
      acc[i][j] = (f32x4){0.f, 0.f, 0.f, 0.f};

  for (int k0 = 0; k0 < K; k0 += 64) {
    __syncthreads();
    const char* ga = gA + (size_t)k0 * 2;
    const char* gb = gB + (size_t)k0 * 2;
    #pragma unroll
    for (int c = 0; c < 4; ++c) {
      gload16(ga + c * stepA, lA + c * 1024);
      gload16(gb + c * stepB, lB + c * 1024);
    }
    __syncthreads();
    #pragma unroll
    for (int kk = 0; kk < 2; ++kk) {
      bf16x8 af[4], bf_[4];
      #pragma unroll
      for (int i = 0; i < 4; ++i) {
        int ar = wm + i * 16 + lrow;
        af[i]  = *(const bf16x8*)((const char*)As + ar * 128 +
                                  ((kk * 64 + kgrp * 16) ^ ((ar & 7) << 4)));
        int br = wn + i * 16 + lrow;
        bf_[i] = *(const bf16x8*)((const char*)Bs + br * 128 +
                                  ((kk * 64 + kgrp * 16) ^ ((br & 7) << 4)));
      }
      #pragma unroll
      for (int i = 0; i < 4; ++i)
        #pragma unroll
        for (int j = 0; j < 4; ++j)
          acc[i][j] = __builtin_amdgcn_mfma_f32_16x16x32_bf16(af[i], bf_[j], acc[i][j], 0, 0, 0);
    }
  }

  // epilogue: C layout col=lane&15, row=(lane>>4)*4+r  [guide m89]
  #pragma unroll
  for (int i = 0; i < 4; ++i) {
    #pragma unroll
    for (int j = 0; j < 4; ++j) {
      #pragma unroll
      for (int r = 0; r < 4; ++r) {
        int m = m0 + wm + i * 16 + kgrp * 4 + r;
        int n = n0 + wn + j * 16 + lrow;
        float v = acc[i][j][r];
        if (bias) v += bias[n];
        if (epi == EPI_F32) {
          outF[(size_t)z * sO + (size_t)m * N + n] = v;
        } else if (epi == EPI_BF16) {
          outB[(size_t)m * N + n] = f2bf(v);
        } else if (epi == EPI_RELU_BF16) {
          outB[(size_t)m * N + n] = f2bf(fmaxf(v, 0.f));
        } else {  // EPI_RES
          float* o = outF + (size_t)z * sO;
          const float* rsd = resid + (size_t)z * sR;
          o[(size_t)m * N + n] = rsd[(size_t)m * N + n] + v;
        }
      }
    }
  }
}

extern "C" void kernel_launch(void* const* d_in, const int* in_sizes, int n_in,
                              void* d_out, int out_size, void* d_ws, size_t ws_size,
                              hipStream_t stream)
{
  const int*   tok  = (const int*)d_in[0];
  const float* emb  = (const float*)d_in[1];
  const float* pos  = (const float*)d_in[2];
  const float* ln1w = (const float*)d_in[3];
  const float* ln1b = (const float*)d_in[4];
  const float* qkvw = (const float*)d_in[5];
  const float* qkvb = (const float*)d_in[6];
  const float* ln2w = (const float*)d_in[7];
  const float* ln2b = (const float*)d_in[8];
  const float* ffaw = (const float*)d_in[9];
  const float* ffab = (const float*)d_in[10];
  const float* ffbw = (const float*)d_in[11];
  const float* ffbb = (const float*)d_in[12];
  const float* outw = (const float*)d_in[13];
  float* out = (float*)d_out;

  // workspace layout (~166 MiB)
  char* p = (char*)d_ws;
  float* h      = (float*)p;  p += (size_t)MT * Dm * 4;          // 16.8 MB
  u16*   a      = (u16*)p;    p += (size_t)MT * Dm * 2;          //  8.4 MB
  u16*   hb     = (u16*)p;    p += (size_t)MT * Dm * 2;          //  8.4 MB
  u16*   qkv    = (u16*)p;    p += (size_t)MT * 3 * Dm * 2;      // 25.2 MB
  u16*   vT     = (u16*)p;    p += (size_t)Bm * Dm * Sm * 2;     //  8.4 MB
  float* scores = (float*)p;  p += (size_t)Bm * Sm * Sm * 4;     // 33.5 MB
  u16*   attn   = (u16*)p;    p += (size_t)Bm * Sm * Sm * 2;     // 16.8 MB
  u16*   f      = (u16*)p;    p += (size_t)MT * Fm * 2;          // 33.5 MB
  u16*   wlb    = (u16*)p;    p += (size_t)(3*Dm*Dm + Fm*Dm + Dm*Fm) * 2;  // 23.1 MB
  u16*   owb    = qkv;  // out_w bf16 (65.5 MB) aliases dead qkv+vT+scores at final GEMM

  embed_kernel<<<MT * Dm / 1024, 256, 0, stream>>>(tok, emb, pos, h);

  for (int l = 0; l < Lm; ++l) {
    cvtw_kernel<<<5632, 256, 0, stream>>>(
        qkvw + (size_t)l * 3 * Dm * Dm, ffaw + (size_t)l * Fm * Dm,
        ffbw + (size_t)l * Dm * Fm, wlb);
    ln_kernel<<<MT, 256, 0, stream>>>(h, ln1w + l * Dm, ln1b + l * Dm, a);
    // qkv = a * qkv_w^T + b  (bf16, [4096][3072])   tiles 32m x 24n
    gemm_kernel<<<dim3(768, 1, 1), 256, 0, stream>>>(
        a, wlb, nullptr, qkv, qkvb + l * 3 * Dm, nullptr,
        3 * Dm, Dm, Dm, Dm, 0, 0, 0, 0, 5, EPI_BF16, 1);
    // scores[b] = q_b * k_b^T (fp32)   tiles 16m x 16n per batch
    gemm_kernel<<<dim3(256, 1, Bm), 256, 0, stream>>>(
        qkv, qkv + Dm, scores, nullptr, nullptr, nullptr,
        Sm, Dm, 3 * Dm, 3 * Dm, (long)Sm * 3 * Dm, (long)Sm * 3 * Dm,
        (long)Sm * Sm, 0, 4, EPI_F32, 0);
    softmax_kernel<<<Bm * Sm, 256, 0, stream>>>(scores, attn);
    vtr_kernel<<<dim3(32, 16, Bm), 256, 0, stream>>>(qkv + 2 * Dm, vT);
    // h += attn * v   tiles 16m x 8n per batch
    gemm_kernel<<<dim3(128, 1, Bm), 256, 0, stream>>>(
        attn, vT, h, nullptr, nullptr, h,
        Dm, Sm, Sm, Sm, (long)Sm * Sm, (long)Dm * Sm,
        (long)Sm * Dm, (long)Sm * Dm, 4, EPI_RES, 0);
    ln_kernel<<<MT, 256, 0, stream>>>(h, ln2w + l * Dm, ln2b + l * Dm, a);
    // f = relu(a * ffa_w^T + b)   tiles 32m x 32n
    gemm_kernel<<<dim3(1024, 1, 1), 256, 0, stream>>>(
        a, wlb + 3 * Dm * Dm, nullptr, f, ffab + l * Fm, nullptr,
        Fm, Dm, Dm, Dm, 0, 0, 0, 0, 5, EPI_RELU_BF16, 1);
    // h += f * ffb_w^T + b   tiles 32m x 8n
    gemm_kernel<<<dim3(256, 1, 1), 256, 0, stream>>>(
        f, wlb + 3 * Dm * Dm + Fm * Dm, h, nullptr, ffbb + l * Dm, h,
        Dm, Fm, Fm, Fm, 0, 0, 0, 0, 5, EPI_RES, 1);
  }

  cvt8_kernel<<<MT * Dm / 2048, 256, 0, stream>>>(h, hb);
  cvt8_kernel<<<Vm * Dm / 2048, 256, 0, stream>>>(outw, owb);
  // logits = h * out_w^T (fp32 out)   tiles 32m x 250n
  gemm_kernel<<<dim3(8000, 1, 1), 256, 0, stream>>>(
      hb, owb, out, nullptr, nullptr, nullptr,
      Vm, Dm, Dm, Dm, 0, 0, 0, 0, 5, EPI_F32, 1);
}